// Round 15
// baseline (3391.637 us; speedup 1.0000x reference)
//
#include <hip/hip_runtime.h>
#include <cstdint>
#include <cstddef>

// ---------------- problem constants ----------------
#define SEQ    512
#define BATCH  128
#define EMB    512
#define HID    1024
#define KTOT   1536   // EMB + HID fused K
#define NOUT   8

// ---------------- decomposition ----------------
// 8 pods x 16 batch rows. Pod = bid&7 (round-robin -> one XCD), 32 col-blocks
// of 128 gate-cols (32 units). Block = 256 thr = 4 waves = K-quarters.
// W: 96 cols in VGPR (288/lane) + 32 cols in LDS. All h-exchange pod-internal;
// runtime XCD verification selects L2-local (plain WB + sc0) vs safe (sc1-WT +
// agent) protocol. Geometry = proven-resident 256 blocks x 1/CU.
#define NPOD   8
#define NCB    32            // col-blocks per pod
#define NBLK   (NPOD*NCB)    // 256
#define ROWS   16            // batch rows per pod/block
#define WLSTR  1544          // LDS W stride (<=2-way on b128 reads)

// s_getreg imm for HW_REG_XCC_ID (id=20, offset=0, size=32) [m09]
#define GETREG_XCC 63508

typedef unsigned short u16;
typedef unsigned int   u32;
typedef __attribute__((ext_vector_type(8))) __bf16 bf16x8;
typedef __attribute__((ext_vector_type(4))) float  f32x4;
typedef __attribute__((ext_vector_type(4))) float  float4v;
typedef __attribute__((ext_vector_type(4))) u16    u16x4;

// ---------------- workspace layout ----------------
#define OFF_X    0ull
#define SZ_X     ((size_t)SEQ*BATCH*EMB*2)       // 64 MB  bf16 x [S][B][E]
#define OFF_W    (OFF_X + SZ_X)
#define SZ_W     ((size_t)4*HID*KTOT*2)          // 12 MB  bf16 Wp[gc][k], gc=unit*4+q
#define OFF_RING (OFF_W + SZ_W)
#define SZ_RING  ((size_t)(SEQ+1)*BATCH*HID*2)   // 134 MB h ring
#define OFF_FW   (OFF_RING + SZ_RING)
#define SZ_FW    ((size_t)NBLK*64)               // 16 KB per-block flag lines
#define OFF_XT   (OFF_FW + SZ_FW)
#define SZ_XT    (4096ull)                       // xcd table
#define WS_NEED  (OFF_XT + SZ_XT)

#define SMEM_W   ((size_t)32*WLSTR*2)            // 98816 B LDS W (32 cols)
#define SMEM_P   ((size_t)4*ROWS*136*4)          // 34816 B pacc
#define SMEM_BYTES (SMEM_W + SMEM_P)

// ---------------- helpers ----------------
__device__ inline u16 f2b(float f) {            // f32 -> bf16 RNE
  uint32_t u = __builtin_bit_cast(uint32_t, f);
  u = u + 0x7FFFu + ((u >> 16) & 1u);
  return (u16)(u >> 16);
}
__device__ inline float b2f(u16 u) {
  uint32_t v = ((uint32_t)u) << 16;
  return __builtin_bit_cast(float, v);
}
__device__ inline float sigm(float x) { return 1.0f / (1.0f + __expf(-x)); }
__device__ inline float tanh_(float x) {
  x = fminf(fmaxf(x, -15.f), 15.f);
  float e = __expf(2.f * x);
  return (e - 1.f) / (e + 1.f);
}
__device__ inline f32x4 mfma16(bf16x8 a, bf16x8 b, f32x4 c) {
  return __builtin_amdgcn_mfma_f32_16x16x32_bf16(a, b, c, 0, 0, 0);
}

// ---------------- prep: embedding gather -> bf16 x[t][b][e] ----------------
__global__ void embed_kernel(const int* __restrict__ ids,
                             const float* __restrict__ emb,
                             u16* __restrict__ x) {
  int bid = blockIdx.x;            // t*128 + b
  int t = bid >> 7, b = bid & 127;
  int idx = ids[b * SEQ + t];
  const float4v* src = (const float4v*)(emb + (size_t)idx * EMB);
  float4v v = src[threadIdx.x];
  u16x4 o;
  o.x = f2b(v.x); o.y = f2b(v.y); o.z = f2b(v.z); o.w = f2b(v.w);
  *(u16x4*)(x + (size_t)bid * EMB + threadIdx.x * 4) = o;
}

// ---------------- prep: pack fused W, unit-major: gc=unit*4+q -----------
__global__ void wpack_kernel(const float* __restrict__ Wih,
                             const float* __restrict__ Whh,
                             u16* __restrict__ Wp) {
  int gc = blockIdx.x;             // 0..4095
  int unit = gc >> 2, q = gc & 3;
  int row = q * HID + unit;
  u16* dst = Wp + (size_t)gc * KTOT;
  for (int k = threadIdx.x; k < KTOT; k += 256) {
    float v = (k < EMB) ? Wih[(size_t)row * EMB + k]
                        : Whh[(size_t)row * HID + (k - EMB)];
    dst[k] = f2b(v);
  }
}

// ---------------- persistent LSTM recurrence (XCD-local pods) --------------
__global__ __launch_bounds__(256, 1) void lstm_kernel(
    const u16* __restrict__ x,     // [SEQ][BATCH][EMB] bf16
    const u16* __restrict__ Wp,    // [4096][KTOT] bf16 packed
    const float* __restrict__ bias,// [4*HID] f32 gate-major
    u16* __restrict__ ring,        // [SEQ+1][BATCH][HID]; ring[0]=0
    u32* __restrict__ fw,          // [NBLK] flag lines (zeroed; monotone)
    u32* __restrict__ xtab)        // [NBLK] xcd table (zeroed)
{
  extern __shared__ char smem[];
  u16*   wl   = (u16*)smem;                    // [32][WLSTR] LDS W cols 96..127
  float* pacc = (float*)(smem + SMEM_W);       // [4][ROWS][136]
  __shared__ int smode;

  const int tid  = threadIdx.x;
  const int bid  = blockIdx.x;
  const int pod  = bid & 7;        // pod (one XCD under round-robin)
  const int cb   = bid >> 3;       // col-block 0..31 (128 gate-cols)
  const int lane = tid & 63;
  const int kq   = tid >> 6;       // wave = K-quarter
  const int l15  = lane & 15;
  const int lhi  = lane >> 4;

  const int nxc  = (kq == 0) ? 12 : (kq == 1 ? 4 : 0);   // x-chunks of slice
  const int arow = pod * ROWS + l15;           // A-fragment batch row

  // ---- publish XCD id (tagged) immediately ----
  const u32 myx = (__builtin_amdgcn_s_getreg(GETREG_XCC) & 0xFu) | 0x10u;
  if (tid == 0) {
    smode = 0;
    __hip_atomic_store(&xtab[bid], myx, __ATOMIC_RELAXED,
                       __HIP_MEMORY_SCOPE_AGENT);
  }

  // ---- W: 96 cols -> registers (288 VGPR) ----
  bf16x8 wreg[12][6];
  {
    const int colbase = cb * 128;
    #pragma unroll
    for (int c = 0; c < 12; ++c)
      #pragma unroll
      for (int nt = 0; nt < 6; ++nt)
        wreg[c][nt] = *(const bf16x8*)(Wp
            + (size_t)(colbase + nt * 16 + l15) * KTOT
            + kq * 384 + c * 32 + lhi * 8);
  }
  // ---- W: cols 96..127 -> LDS ----
  for (int e = tid * 8; e < 32 * KTOT; e += 256 * 8) {
    int col = e / KTOT;
    int k   = e - col * KTOT;
    *(bf16x8*)&wl[col * WLSTR + k] =
        *(const bf16x8*)(Wp + (size_t)(cb * 128 + 96 + col) * KTOT + k);
  }

  // ---- verdict: are all 32 pod peers on my XCD? (uniform per pod) ----
  __syncthreads();                 // smode init + wl staged
  if (tid < 64) {
    const int peer = 8 * (lane & 31) + pod;
    u32 xv = 0; int bail = 0;
    for (;;) {
      xv = __hip_atomic_load(&xtab[peer], __ATOMIC_RELAXED,
                             __HIP_MEMORY_SCOPE_AGENT);
      if (xv != 0) break;
      if (++bail > (1 << 18)) break;
      __builtin_amdgcn_s_sleep(1);
    }
    int ok = __all(xv == myx) ? 1 : 0;
    if (lane == 0) smode = ok;
  }
  __syncthreads();
  const int fast = smode;

  // ---- cell mapping: thread -> (row urow, units u, u+16) ----
  const int urow = tid >> 4;                   // 0..15
  const int u    = tid & 15;
  float bs[2][4];
  #pragma unroll
  for (int k = 0; k < 2; ++k) {
    int ug = cb * 32 + u + k * 16;
    #pragma unroll
    for (int q = 0; q < 4; ++q) bs[k][q] = bias[q * HID + ug];
  }
  float cst[2] = {0.f, 0.f};

  const u16* wlb  = &wl[l15 * WLSTR + kq * 384 + lhi * 8];   // tile6 base
  u32* fw_own = &fw[(size_t)bid * 16];

  // ---- prologue: x fragments for t=0 ----
  bf16x8 af[12];
  #pragma unroll
  for (int c = 0; c < 12; ++c)
    if (c < nxc)
      af[c] = *(const bf16x8*)(x + (size_t)arow * EMB + kq * 384 + c * 32 + lhi * 8);

  #pragma unroll 1
  for (int t = 0; t < SEQ; ++t) {
    // ---- A: pre-poll x-part MFMAs (absorb skew) ----
    f32x4 acc[8];
    #pragma unroll
    for (int nt = 0; nt < 8; ++nt) acc[nt] = (f32x4){0.f, 0.f, 0.f, 0.f};
    #pragma unroll
    for (int c = 0; c < 12; ++c)
      if (c < nxc) {
        #pragma unroll
        for (int nt = 0; nt < 6; ++nt)
          acc[nt] = mfma16(af[c], wreg[c][nt], acc[nt]);
        bf16x8 w6 = *(const bf16x8*)(wlb + c * 32);
        bf16x8 w7 = *(const bf16x8*)(wlb + 16 * WLSTR + c * 32);
        acc[6] = mfma16(af[c], w6, acc[6]);
        acc[7] = mfma16(af[c], w7, acc[7]);
      }

    // ---- B: poll pod peers' flags (wave0), then release block ----
    if (t > 0) {
      if (tid < 64) {
        const u32 tgt = (u32)t;
        const u32* fp = &fw[(size_t)(8 * (lane & 31) + pod) * 16];
        int bail = 0;
        if (fast) {
          for (;;) {
            u32 v;
            asm volatile("global_load_dword %0, %1, off sc0\n\t"
                         "s_waitcnt vmcnt(0)"
                         : "=v"(v) : "v"(fp) : "memory");
            if (__all(v >= tgt)) break;
            if (++bail > (1 << 18)) break;
            __builtin_amdgcn_s_sleep(1);
          }
        } else {
          for (;;) {
            u32 v = __hip_atomic_load(fp, __ATOMIC_RELAXED,
                                      __HIP_MEMORY_SCOPE_AGENT);
            if (__all(v >= tgt)) break;
            if (++bail > (1 << 18)) break;
            __builtin_amdgcn_s_sleep(1);
          }
        }
        __asm__ __volatile__("" ::: "memory");
      }
      __syncthreads();
    }

    // ---- C: h loads (plain cached; ring lines fresh; pod-local in fast) ----
    {
      const u16* hb = ring + (size_t)t * (BATCH * HID);
      #pragma unroll
      for (int c = 0; c < 12; ++c)
        if (c >= nxc)
          af[c] = *(const bf16x8*)(hb + (size_t)arow * HID
                                   + (kq * 384 - 512 + c * 32) + lhi * 8);
    }

    // ---- D: x prefetch t+1 ----
    {
      int tn = (t + 1 < SEQ) ? (t + 1) : t;
      const u16* xb = x + (size_t)tn * (BATCH * EMB);
      #pragma unroll
      for (int c = 0; c < 12; ++c)
        if (c < nxc)
          af[c] = *(const bf16x8*)(xb + (size_t)arow * EMB
                                   + kq * 384 + c * 32 + lhi * 8);
    }

    // ---- E: h-part MFMAs ----
    #pragma unroll
    for (int c = 0; c < 12; ++c)
      if (c >= nxc) {
        #pragma unroll
        for (int nt = 0; nt < 6; ++nt)
          acc[nt] = mfma16(af[c], wreg[c][nt], acc[nt]);
        bf16x8 w6 = *(const bf16x8*)(wlb + c * 32);
        bf16x8 w7 = *(const bf16x8*)(wlb + 16 * WLSTR + c * 32);
        acc[6] = mfma16(af[c], w6, acc[6]);
        acc[7] = mfma16(af[c], w7, acc[7]);
      }

    // ---- F: partials -> LDS (XOR col swizzle) ----
    #pragma unroll
    for (int nt = 0; nt < 8; ++nt)
      #pragma unroll
      for (int rr = 0; rr < 4; ++rr) {
        int row = lhi * 4 + rr;
        int c   = nt * 16 + l15;
        int pc  = (c & ~7) | ((c ^ row) & 7);
        pacc[(kq * ROWS + row) * 136 + pc] = acc[nt][rr];
      }
    __syncthreads();                         // sync1: F-writes visible

    // ---- G1: reduce over kq ----
    float s[2][4];
    #pragma unroll
    for (int k = 0; k < 2; ++k)
      #pragma unroll
      for (int q = 0; q < 4; ++q) s[k][q] = bs[k][q];
    #pragma unroll
    for (int k2 = 0; k2 < 4; ++k2)
      #pragma unroll
      for (int k = 0; k < 2; ++k)
        #pragma unroll
        for (int q = 0; q < 4; ++q) {
          int c  = (u + k * 16) * 4 + q;
          int pc = (c & ~7) | ((c ^ urow) & 7);
          s[k][q] += pacc[(k2 * ROWS + urow) * 136 + pc];
        }
    __syncthreads();                         // sync2: pacc reads done

    // ---- G2: cell update + packed store (mode-selected) ----
    {
      float hv2[2];
      #pragma unroll
      for (int k = 0; k < 2; ++k) {
        float cn = sigm(s[k][1]) * cst[k] + sigm(s[k][0]) * tanh_(s[k][2]);
        cst[k] = cn;
        hv2[k] = sigm(s[k][3]) * tanh_(cn);
      }
      float o0 = __shfl_xor(hv2[0], 1);      // unit partner u^1, same row
      float o1 = __shfl_xor(hv2[1], 1);
      if ((u & 1) == 0) {
        u16* hw = ring + (size_t)(t + 1) * (BATCH * HID)
                  + (size_t)(pod * ROWS + urow) * HID + cb * 32;
        u32 v0 = (u32)f2b(hv2[0]) | ((u32)f2b(o0) << 16);
        u32 v1 = (u32)f2b(hv2[1]) | ((u32)f2b(o1) << 16);
        u32* d0 = (u32*)&hw[u];
        u32* d1 = (u32*)&hw[u + 16];
        if (fast) {
          asm volatile("global_store_dword %0, %2, off\n\t"
                       "global_store_dword %1, %3, off"
                       :: "v"(d0), "v"(d1), "v"(v0), "v"(v1) : "memory");
        } else {
          asm volatile("global_store_dword %0, %2, off sc0 sc1\n\t"
                       "global_store_dword %1, %3, off sc0 sc1"
                       :: "v"(d0), "v"(d1), "v"(v0), "v"(v1) : "memory");
        }
      }
    }
    asm volatile("s_waitcnt vmcnt(0)" ::: "memory");  // wave's stores in L2/L3

    __syncthreads();                         // sync3: whole block drained
    if (t == SEQ - 1) break;
    if (tid == 0) {
      u32 v = (u32)(t + 1);
      if (fast) {
        asm volatile("global_store_dword %0, %1, off sc0"
                     :: "v"(fw_own), "v"(v) : "memory");
      } else {
        __hip_atomic_store(fw_own, v, __ATOMIC_RELAXED,
                           __HIP_MEMORY_SCOPE_AGENT);
      }
    }
  }
}

// ---------------- classifier head: out = h_last @ W_out^T + b_out ----------
__global__ void head_kernel(const u16* __restrict__ h,
                            const float* __restrict__ Wout,
                            const float* __restrict__ bout,
                            float* __restrict__ out) {
  int b = blockIdx.x, l = threadIdx.x;
  float p[NOUT];
  #pragma unroll
  for (int o = 0; o < NOUT; ++o) p[o] = 0.f;
  for (int k = l; k < HID; k += 64) {
    float hv = b2f(h[(size_t)b * HID + k]);
    #pragma unroll
    for (int o = 0; o < NOUT; ++o) p[o] += hv * Wout[(size_t)o * HID + k];
  }
  #pragma unroll
  for (int o = 0; o < NOUT; ++o) {
    float v = p[o];
    #pragma unroll
    for (int off = 32; off > 0; off >>= 1) v += __shfl_down(v, off);
    if (l == 0) out[b * NOUT + o] = v + bout[o];
  }
}

// sentinel if workspace too small (distinguishable absmax ~1e9)
__global__ void sentinel_kernel(float* out, int n) {
  int i = blockIdx.x * 256 + threadIdx.x;
  if (i < n) out[i] = 1e9f;
}

extern "C" void kernel_launch(void* const* d_in, const int* in_sizes, int n_in,
                              void* d_out, int out_size, void* d_ws, size_t ws_size,
                              hipStream_t stream) {
  const int*   ids  = (const int*)d_in[0];
  const float* emb  = (const float*)d_in[1];
  const float* Wih  = (const float*)d_in[2];
  const float* Whh  = (const float*)d_in[3];
  const float* bias = (const float*)d_in[4];
  const float* Wout = (const float*)d_in[5];
  const float* bout = (const float*)d_in[6];
  float* out = (float*)d_out;

  if (ws_size < WS_NEED) {
    sentinel_kernel<<<(out_size + 255) / 256, 256, 0, stream>>>(out, out_size);
    return;
  }

  char* ws = (char*)d_ws;
  u16* x    = (u16*)(ws + OFF_X);
  u16* Wp   = (u16*)(ws + OFF_W);
  u16* ring = (u16*)(ws + OFF_RING);
  u32* fwv  = (u32*)(ws + OFF_FW);
  u32* xtab = (u32*)(ws + OFF_XT);

  hipMemsetAsync(ring, 0, (size_t)BATCH * HID * 2, stream);  // ring[0] = h_0 = 0
  hipMemsetAsync(fwv, 0, SZ_FW + SZ_XT, stream);             // flags + xtab

  embed_kernel<<<SEQ * BATCH, 128, 0, stream>>>(ids, emb, x);
  wpack_kernel<<<4 * HID, 256, 0, stream>>>(Wih, Whh, Wp);

  hipFuncSetAttribute((const void*)lstm_kernel,
                      hipFuncAttributeMaxDynamicSharedMemorySize,
                      (int)SMEM_BYTES);
  lstm_kernel<<<NBLK, 256, SMEM_BYTES, stream>>>(x, Wp, bias, ring, fwv, xtab);

  head_kernel<<<BATCH, 64, 0, stream>>>(ring + (size_t)SEQ * BATCH * HID,
                                        Wout, bout, out);
}